// Round 10
// baseline (426.110 us; speedup 1.0000x reference)
//
#include <hip/hip_runtime.h>

#define N_PIX   (32 * 64 * 64)          // 131072 pixel rows
#define E_DIM   64
#define N_E     1024
#define Z_ELEMS (N_PIX * E_DIM)         // 8388608
#define TC      32                      // codes per LDS tile (8 KB/tile)
#define NT      (N_E / TC)              // 32 tiles
#define PPB     64                      // pixels per block (4 lanes/px, P=1)

#define LOSS_OFF 0
#define ZQ_OFF   1
#define PERP_OFF (1 + Z_ELEMS)                          // 8388609
#define ENC_OFF  ((size_t)(2 + Z_ELEMS))                // 8388610
#define IDX_OFF  (ENC_OFF + (size_t)N_PIX * N_E)        // 142606338

typedef float f32x2 __attribute__((ext_vector_type(2)));
typedef float f32x4 __attribute__((ext_vector_type(4)));

// cross-lane adds within each 4-lane group (VALU pipe, no LDS traffic)
__device__ __forceinline__ float dpp_add_xor1(float v) {
    int i = __builtin_bit_cast(int, v);
    i = __builtin_amdgcn_mov_dpp(i, 0xB1, 0xF, 0xF, true);  // quad_perm(1,0,3,2)
    return v + __builtin_bit_cast(float, i);
}
__device__ __forceinline__ float dpp_add_xor2(float v) {
    int i = __builtin_bit_cast(int, v);
    i = __builtin_amdgcn_mov_dpp(i, 0x4E, 0xF, 0xF, true);  // quad_perm(2,3,0,1)
    return v + __builtin_bit_cast(float, i);
}

// ---- precompute ||e||^2 per codebook row ----
__global__ void vq_prep(const float* __restrict__ emb, float* __restrict__ ee) {
    int e = blockIdx.x * blockDim.x + threadIdx.x;
    if (e < N_E) {
        const float* r = emb + e * E_DIM;
        float s0 = 0.f, s1 = 0.f, s2 = 0.f, s3 = 0.f;
        #pragma unroll
        for (int c = 0; c < E_DIM; c += 4) {
            s0 = fmaf(r[c],     r[c],     s0);
            s1 = fmaf(r[c + 1], r[c + 1], s1);
            s2 = fmaf(r[c + 2], r[c + 2], s2);
            s3 = fmaf(r[c + 3], r[c + 3], s3);
        }
        ee[e] = (s0 + s1) + (s2 + s3);
    }
}

// ---- main: 4 lanes/pixel, P=1, small LDS tiles for 8 blocks/CU ----
// R9 was grid-occupancy-capped: 1024 blocks / 256 CU = 4 blocks/CU (50% max,
// 33% measured) with 26% idle. TC=32 (16.5 KB LDS) + PPB=64 gives 2048 blocks
// = 8 blocks/CU = 8 waves/SIMD. Numerics: R5/R9's exact tree (quarter chains,
// quad DPP, zz + ee - 2*dot) retained bit-for-bit.
__global__ __launch_bounds__(256, 8) void vq_main(
    const float* __restrict__ z, const float* __restrict__ emb,
    const float* __restrict__ ee, float* __restrict__ out,
    unsigned* __restrict__ counts, double* __restrict__ loss_acc)
{
    __shared__ float lds[2][TC * E_DIM];    // 2 x 8 KB
    __shared__ int   sbest[PPB];

    const int tid = threadIdx.x;
    const int s   = tid & 3;                // channel quarter 0..3
    const int pl  = tid >> 2;               // local pixel 0..63
    const int p0  = blockIdx.x * PPB + pl;  // global pixel = b*4096 + hw
    const int b   = p0 >> 12;
    const int hw  = p0 & 4095;

    // ---- my 16 channels of z (stride 4096; coalesced across lanes) ----
    const float* zp = z + ((size_t)b * E_DIM + s * 16) * 4096 + hw;
    f32x4 zv[4];
    #pragma unroll
    for (int m = 0; m < 4; ++m) {
        #pragma unroll
        for (int q = 0; q < 4; ++q)
            zv[m][q] = zp[(size_t)(4 * m + q) * 4096];
    }

    // ---- zz (R5 tree: chained vec-fma, pairwise combine, quad DPP) ----
    float zz;
    {
        f32x4 za = {0.f,0.f,0.f,0.f};
        #pragma unroll
        for (int j = 0; j < 4; ++j) za = __builtin_elementwise_fma(zv[j], zv[j], za);
        f32x2 zt = __builtin_shufflevector(za, za, 0, 1)
                 + __builtin_shufflevector(za, za, 2, 3);
        zz = dpp_add_xor2(dpp_add_xor1(zt.x + zt.y));
    }

    // ---- argmin over codes, tile-by-tile (double-buffered LDS) ----
    float dmin = 3.4e38f;
    int   best = 0;
    f32x4 st[2];

    {   // prologue: stage tile 0 (512 f32x4 covered by 256 threads x2)
        const f32x4* gt = (const f32x4*)emb;
        #pragma unroll
        for (int j = 0; j < 2; ++j) st[j] = gt[j * 256 + tid];
        f32x4* lt = (f32x4*)lds[0];
        #pragma unroll
        for (int j = 0; j < 2; ++j) lt[j * 256 + tid] = st[j];
    }
    __syncthreads();

    for (int t = 0; t < NT; ++t) {
        const int cur = t & 1;
        if (t + 1 < NT) {   // T14: issue next tile's global loads BEFORE compute
            const f32x4* gt = (const f32x4*)(emb + (t + 1) * (TC * E_DIM));
            #pragma unroll
            for (int j = 0; j < 2; ++j) st[j] = gt[j * 256 + tid];
        }
        const f32x4* rows = (const f32x4*)lds[cur];
        const float* eet  = ee + t * TC;
        #pragma unroll 4
        for (int k = 0; k < TC; ++k) {
            const f32x4* rp = rows + k * 16 + s * 4;   // my 16-ch quarter
            f32x4 a = {0.f,0.f,0.f,0.f};
            #pragma unroll
            for (int j = 0; j < 4; ++j) a = __builtin_elementwise_fma(zv[j], rp[j], a);
            f32x2 t2 = __builtin_shufflevector(a, a, 0, 1)
                     + __builtin_shufflevector(a, a, 2, 3);
            const float dot = dpp_add_xor2(dpp_add_xor1(t2.x + t2.y));
            const float d = zz + eet[k] - 2.0f * dot;     // ref-matching rounding
            if (d < dmin) { dmin = d; best = t * TC + k; } // first-index ties
        }
        if (t + 1 < NT) {
            f32x4* lt = (f32x4*)lds[cur ^ 1];
            #pragma unroll
            for (int j = 0; j < 2; ++j) lt[j * 256 + tid] = st[j];
        }
        __syncthreads();
    }

    // ---- index + histogram (group leader; best uniform across the quad) ----
    if (s == 0) {
        out[IDX_OFF + p0] = (float)best;
        atomicAdd(&counts[best], 1u);
    }

    // ---- z_q (NCHW, NT stores) + loss partial over my 16 channels ----
    float lsum;
    {
        const f32x4* eb = (const f32x4*)(emb + best * E_DIM) + s * 4;
        float* zqp = out + ZQ_OFF + ((size_t)b * E_DIM + s * 16) * 4096 + hw;
        f32x4 la = {0.f,0.f,0.f,0.f};
        #pragma unroll
        for (int m = 0; m < 4; ++m) {
            f32x4 q = eb[m];
            #pragma unroll
            for (int qi = 0; qi < 4; ++qi)
                __builtin_nontemporal_store(q[qi], &zqp[(size_t)(4 * m + qi) * 4096]);
            f32x4 dq = q - zv[m];
            la = __builtin_elementwise_fma(dq, dq, la);
        }
        lsum = (la[0] + la[2]) + (la[1] + la[3]);
    }
    #pragma unroll
    for (int o = 32; o > 0; o >>= 1) lsum += __shfl_down(lsum, o);
    if ((tid & 63) == 0) atomicAdd(loss_acc, (double)lsum);

    // ---- one-hot: block writes its 64 rows cooperatively, coalesced NT ----
    if (s == 0) sbest[pl] = best;
    __syncthreads();
    const size_t blockbase = ENC_OFF + (size_t)blockIdx.x * PPB * N_E;
    const int col = tid * 4;
    for (int r = 0; r < PPB; ++r) {
        const int rb = sbest[r];
        f32x2 v0 = { rb == col     ? 1.f : 0.f, rb == col + 1 ? 1.f : 0.f };
        f32x2 v1 = { rb == col + 2 ? 1.f : 0.f, rb == col + 3 ? 1.f : 0.f };
        float* dst = out + blockbase + (size_t)r * N_E + col;
        __builtin_nontemporal_store(v0, (f32x2*)dst);
        __builtin_nontemporal_store(v1, (f32x2*)(dst + 2));
    }
}

// ---- finalize: perplexity + loss ----
__global__ void vq_final(const unsigned* __restrict__ counts,
                         const double* __restrict__ loss_acc,
                         float* __restrict__ out)
{
    __shared__ float red[N_E];
    const int e = threadIdx.x;
    const float em = (float)counts[e] * (1.0f / (float)N_PIX);
    red[e] = em * logf(em + 1e-10f);
    __syncthreads();
    for (int s = 512; s > 0; s >>= 1) {
        if (e < s) red[e] += red[e + s];
        __syncthreads();
    }
    if (e == 0) {
        out[PERP_OFF] = expf(-red[0]);
        out[LOSS_OFF] = (float)((*loss_acc) * (1.25 / (double)Z_ELEMS));
    }
}

extern "C" void kernel_launch(void* const* d_in, const int* in_sizes, int n_in,
                              void* d_out, int out_size, void* d_ws, size_t ws_size,
                              hipStream_t stream) {
    const float* z   = (const float*)d_in[0];
    const float* emb = (const float*)d_in[1];
    float* out = (float*)d_out;

    unsigned* counts   = (unsigned*)d_ws;                   // 4096 B
    double*   loss_acc = (double*)((char*)d_ws + 4096);     // 8 B
    float*    ee       = (float*)((char*)d_ws + 8192);      // 4096 B

    (void)hipMemsetAsync(d_ws, 0, 4104, stream);
    vq_prep<<<4, 256, 0, stream>>>(emb, ee);
    vq_main<<<N_PIX / PPB, 256, 0, stream>>>(z, emb, ee, out, counts, loss_acc);
    vq_final<<<1, N_E, 0, stream>>>(counts, loss_acc, out);
}

// Round 12
// 380.513 us; speedup vs baseline: 1.1198x; 1.1198x over previous
//
#include <hip/hip_runtime.h>

#define N_PIX   (32 * 64 * 64)          // 131072 pixel rows
#define E_DIM   64
#define N_E     1024
#define Z_ELEMS (N_PIX * E_DIM)         // 8388608
#define TC      64                      // codes per LDS tile
#define NT      (N_E / TC)              // 16 tiles
#define PPB     128                     // pixels per block (4 lanes/px, P=2)

#define LOSS_OFF 0
#define ZQ_OFF   1
#define PERP_OFF (1 + Z_ELEMS)                          // 8388609
#define ENC_OFF  ((size_t)(2 + Z_ELEMS))                // 8388610
#define IDX_OFF  (ENC_OFF + (size_t)N_PIX * N_E)        // 142606338

typedef float f32x2 __attribute__((ext_vector_type(2)));
typedef float f32x4 __attribute__((ext_vector_type(4)));

// cross-lane adds within each 4-lane group (VALU pipe, no LDS traffic)
__device__ __forceinline__ float dpp_add_xor1(float v) {
    int i = __builtin_bit_cast(int, v);
    i = __builtin_amdgcn_mov_dpp(i, 0xB1, 0xF, 0xF, true);  // quad_perm(1,0,3,2)
    return v + __builtin_bit_cast(float, i);
}
__device__ __forceinline__ float dpp_add_xor2(float v) {
    int i = __builtin_bit_cast(int, v);
    i = __builtin_amdgcn_mov_dpp(i, 0x4E, 0xF, 0xF, true);  // quad_perm(2,3,0,1)
    return v + __builtin_bit_cast(float, i);
}

// ---- precompute ||e||^2 per codebook row ----
__global__ void vq_prep(const float* __restrict__ emb, float* __restrict__ ee) {
    int e = blockIdx.x * blockDim.x + threadIdx.x;
    if (e < N_E) {
        const float* r = emb + e * E_DIM;
        float s0 = 0.f, s1 = 0.f, s2 = 0.f, s3 = 0.f;
        #pragma unroll
        for (int c = 0; c < E_DIM; c += 4) {
            s0 = fmaf(r[c],     r[c],     s0);
            s1 = fmaf(r[c + 1], r[c + 1], s1);
            s2 = fmaf(r[c + 2], r[c + 2], s2);
            s3 = fmaf(r[c + 3], r[c + 3], s3);
        }
        ee[e] = (s0 + s1) + (s2 + s3);
    }
}

// ---- main: R9's exact numerics (FROZEN — R11 lesson: any fp-tree change
// risks argmin tie flips). New: one-hot zero-fill streamed during the argmin
// loop (NT stores hidden under compute), one-hot value phase reduced to one
// scattered 1.0/pixel; 128-iteration epilogue loop removed.
__global__ __launch_bounds__(256, 4) void vq_main(
    const float* __restrict__ z, const float* __restrict__ emb,
    const float* __restrict__ ee, float* __restrict__ out,
    unsigned* __restrict__ counts, double* __restrict__ loss_acc)
{
    __shared__ float lds[2][TC * E_DIM];    // 2 x 16 KB

    const int tid = threadIdx.x;
    const int s   = tid & 3;                // channel quarter 0..3
    const int pl  = tid >> 2;               // local pixel 0..63
    const int p0  = blockIdx.x * PPB + pl;  // pixels p0 and p0+64 (same image)
    const int b   = p0 >> 12;
    const int hw  = p0 & 4095;              // second pixel at hw+64 (no wrap)

    // ---- my 16 channels of z for both pixels (stride 4096) ----
    const float* zp = z + ((size_t)b * E_DIM + s * 16) * 4096 + hw;
    f32x4 zv0[4], zv1[4];
    #pragma unroll
    for (int m = 0; m < 4; ++m) {
        #pragma unroll
        for (int q = 0; q < 4; ++q) {
            zv0[m][q] = zp[(size_t)(4 * m + q) * 4096];
            zv1[m][q] = zp[(size_t)(4 * m + q) * 4096 + 64];
        }
    }

    // ---- zz per pixel (R5/R9 tree, frozen) ----
    float zz0, zz1;
    {
        f32x4 za = {0.f,0.f,0.f,0.f};
        #pragma unroll
        for (int j = 0; j < 4; ++j) za = __builtin_elementwise_fma(zv0[j], zv0[j], za);
        f32x2 zt = __builtin_shufflevector(za, za, 0, 1)
                 + __builtin_shufflevector(za, za, 2, 3);
        zz0 = dpp_add_xor2(dpp_add_xor1(zt.x + zt.y));
    }
    {
        f32x4 za = {0.f,0.f,0.f,0.f};
        #pragma unroll
        for (int j = 0; j < 4; ++j) za = __builtin_elementwise_fma(zv1[j], zv1[j], za);
        f32x2 zt = __builtin_shufflevector(za, za, 0, 1)
                 + __builtin_shufflevector(za, za, 2, 3);
        zz1 = dpp_add_xor2(dpp_add_xor1(zt.x + zt.y));
    }

    // ---- argmin over codes, tile-by-tile (double-buffered LDS) ----
    float dmin0 = 3.4e38f, dmin1 = 3.4e38f;
    int   best0 = 0, best1 = 0;
    f32x4 st[4];

    {   // prologue: stage tile 0 (1024 f32x4 covered by 256 threads x4)
        const f32x4* gt = (const f32x4*)emb;
        #pragma unroll
        for (int j = 0; j < 4; ++j) st[j] = gt[j * 256 + tid];
        f32x4* lt = (f32x4*)lds[0];
        #pragma unroll
        for (int j = 0; j < 4; ++j) lt[j * 256 + tid] = st[j];
    }
    __syncthreads();

    // one-hot zero region of this block: 128 rows x 1024 cols, even base
    const size_t zb = ENC_OFF + (size_t)blockIdx.x * PPB * N_E;

    for (int t = 0; t < NT; ++t) {
        const int cur = t & 1;
        if (t + 1 < NT) {   // T14: issue next tile's global loads BEFORE compute
            const f32x4* gt = (const f32x4*)(emb + (t + 1) * (TC * E_DIM));
            #pragma unroll
            for (int j = 0; j < 4; ++j) st[j] = gt[j * 256 + tid];
        }
        const f32x4* rows = (const f32x4*)lds[cur];
        const float* eet  = ee + t * TC;
        #pragma unroll 4
        for (int k = 0; k < TC; ++k) {
            f32x4 row[4];
            const f32x4* rp = rows + k * 16 + s * 4;   // my 16-ch quarter
            #pragma unroll
            for (int j = 0; j < 4; ++j) row[j] = rp[j];   // broadcast, 0-conflict

            // pixel 0 (frozen tree)
            {
                f32x4 a = {0.f,0.f,0.f,0.f};
                #pragma unroll
                for (int j = 0; j < 4; ++j) a = __builtin_elementwise_fma(zv0[j], row[j], a);
                f32x2 t2 = __builtin_shufflevector(a, a, 0, 1)
                         + __builtin_shufflevector(a, a, 2, 3);
                const float dot = dpp_add_xor2(dpp_add_xor1(t2.x + t2.y));
                const float d = zz0 + eet[k] - 2.0f * dot;
                if (d < dmin0) { dmin0 = d; best0 = t * TC + k; }
            }
            // pixel 1 (same tree)
            {
                f32x4 a = {0.f,0.f,0.f,0.f};
                #pragma unroll
                for (int j = 0; j < 4; ++j) a = __builtin_elementwise_fma(zv1[j], row[j], a);
                f32x2 t2 = __builtin_shufflevector(a, a, 0, 1)
                         + __builtin_shufflevector(a, a, 2, 3);
                const float dot = dpp_add_xor2(dpp_add_xor1(t2.x + t2.y));
                const float d = zz1 + eet[k] - 2.0f * dot;
                if (d < dmin1) { dmin1 = d; best1 = t * TC + k; }
            }
        }

        // ---- streamed one-hot zero-fill: 16 coalesced f32x2 NT stores per
        // thread per tile (4096 units/tile x 16 tiles = 65536 = 512 KB/block).
        // Fire-and-forget; HBM writes overlap the next tile's compute.
        {
            const f32x2 zval = {0.f, 0.f};
            const size_t u0 = (size_t)t * 4096 + tid;
            #pragma unroll
            for (int j = 0; j < 16; ++j)
                __builtin_nontemporal_store(zval, (f32x2*)(out + zb + (u0 + j * 256) * 2));
        }

        if (t + 1 < NT) {
            f32x4* lt = (f32x4*)lds[cur ^ 1];
            #pragma unroll
            for (int j = 0; j < 4; ++j) lt[j * 256 + tid] = st[j];
        }
        __syncthreads();   // also drains this tile's NT zero stores (vmcnt 0)
    }

    // ---- one-hot ones: a single scattered 1.0 per pixel (zeros all landed
    // before the final barrier; same-CU same-address ordering is safe) ----
    if (s == 0) {
        out[zb + (size_t)pl * N_E + best0]        = 1.0f;
        out[zb + (size_t)(pl + 64) * N_E + best1] = 1.0f;
        out[IDX_OFF + p0]      = (float)best0;
        out[IDX_OFF + p0 + 64] = (float)best1;
        atomicAdd(&counts[best0], 1u);
        atomicAdd(&counts[best1], 1u);
    }

    // ---- z_q (NCHW, NT stores) + loss partials over my 16 channels ----
    float lsum;
    {
        const f32x4* eb0 = (const f32x4*)(emb + best0 * E_DIM) + s * 4;
        const f32x4* eb1 = (const f32x4*)(emb + best1 * E_DIM) + s * 4;
        float* zqp = out + ZQ_OFF + ((size_t)b * E_DIM + s * 16) * 4096 + hw;
        f32x4 la0 = {0.f,0.f,0.f,0.f}, la1 = {0.f,0.f,0.f,0.f};
        #pragma unroll
        for (int m = 0; m < 4; ++m) {
            f32x4 q0 = eb0[m], q1 = eb1[m];
            #pragma unroll
            for (int q = 0; q < 4; ++q) {
                __builtin_nontemporal_store(q0[q], &zqp[(size_t)(4 * m + q) * 4096]);
                __builtin_nontemporal_store(q1[q], &zqp[(size_t)(4 * m + q) * 4096 + 64]);
            }
            f32x4 dq0 = q0 - zv0[m], dq1 = q1 - zv1[m];
            la0 = __builtin_elementwise_fma(dq0, dq0, la0);
            la1 = __builtin_elementwise_fma(dq1, dq1, la1);
        }
        lsum = ((la0[0] + la0[2]) + (la0[1] + la0[3]))
             + ((la1[0] + la1[2]) + (la1[1] + la1[3]));
    }
    #pragma unroll
    for (int o = 32; o > 0; o >>= 1) lsum += __shfl_down(lsum, o);
    if ((tid & 63) == 0) atomicAdd(loss_acc, (double)lsum);
}

// ---- finalize: perplexity + loss ----
__global__ void vq_final(const unsigned* __restrict__ counts,
                         const double* __restrict__ loss_acc,
                         float* __restrict__ out)
{
    __shared__ float red[N_E];
    const int e = threadIdx.x;
    const float em = (float)counts[e] * (1.0f / (float)N_PIX);
    red[e] = em * logf(em + 1e-10f);
    __syncthreads();
    for (int s = 512; s > 0; s >>= 1) {
        if (e < s) red[e] += red[e + s];
        __syncthreads();
    }
    if (e == 0) {
        out[PERP_OFF] = expf(-red[0]);
        out[LOSS_OFF] = (float)((*loss_acc) * (1.25 / (double)Z_ELEMS));
    }
}

extern "C" void kernel_launch(void* const* d_in, const int* in_sizes, int n_in,
                              void* d_out, int out_size, void* d_ws, size_t ws_size,
                              hipStream_t stream) {
    const float* z   = (const float*)d_in[0];
    const float* emb = (const float*)d_in[1];
    float* out = (float*)d_out;

    unsigned* counts   = (unsigned*)d_ws;                   // 4096 B
    double*   loss_acc = (double*)((char*)d_ws + 4096);     // 8 B
    float*    ee       = (float*)((char*)d_ws + 8192);      // 4096 B

    (void)hipMemsetAsync(d_ws, 0, 4104, stream);
    vq_prep<<<4, 256, 0, stream>>>(emb, ee);
    vq_main<<<N_PIX / PPB, 256, 0, stream>>>(z, emb, ee, out, counts, loss_acc);
    vq_final<<<1, N_E, 0, stream>>>(counts, loss_acc, out);
}